// Round 10
// baseline (198.545 us; speedup 1.0000x reference)
//
#include <hip/hip_runtime.h>
#include <math.h>
#include <stdint.h>

// Problem constants (B=2, S=2048, D=1024, H=16, HD=64)
constexpr int BB  = 2;
constexpr int SS  = 2048;
constexpr int DD  = 1024;
constexpr int HH  = 16;
constexpr int HDD = 64;
constexpr int MM  = BB * SS; // 4096

typedef uint16_t u16;
typedef __attribute__((ext_vector_type(4))) float    f32x4;
typedef __attribute__((ext_vector_type(8))) _Float16 f16x8;
typedef __attribute__((ext_vector_type(4))) _Float16 f16x4;
typedef __attribute__((ext_vector_type(8))) short    s16x8;
typedef __attribute__((ext_vector_type(4))) unsigned int u32x4;

__device__ __forceinline__ u16 to_f16(float f) {
    const _Float16 h = (_Float16)f;          // v_cvt_f16_f32, RNE
    return __builtin_bit_cast(u16, h);
}

__device__ __forceinline__ f32x4 mfma32(s16x8 a, s16x8 b, f32x4 c) {
    return __builtin_amdgcn_mfma_f32_16x16x32_f16(
        __builtin_bit_cast(f16x8, a), __builtin_bit_cast(f16x8, b), c, 0, 0, 0);
}
__device__ __forceinline__ f32x4 mfma32_ff(s16x8 a, f16x8 b, f32x4 c) {
    return __builtin_amdgcn_mfma_f32_16x16x32_f16(
        __builtin_bit_cast(f16x8, a), b, c, 0, 0, 0);
}

// async global->LDS, 16B per lane; LDS dest = wave-uniform base + lane*16
__device__ __forceinline__ void load_lds16(const void* g, void* l) {
    __builtin_amdgcn_global_load_lds(
        (const __attribute__((address_space(1))) void*)g,
        (__attribute__((address_space(3))) void*)l, 16, 0, 0);
}

// ---------------------------------------------------------------------------
// fp32 -> fp16 cast, all 5 tensors in one launch.
// blocks 0..2047: x (4M elems); blocks 2048..4095: wq,wk,wv,wo (1M each).
// ---------------------------------------------------------------------------
__global__ __launch_bounds__(256) void cast_all(
    const float* __restrict__ x,
    const float* __restrict__ w0, const float* __restrict__ w1,
    const float* __restrict__ w2, const float* __restrict__ w3,
    u16* __restrict__ xb, u16* __restrict__ wb)
{
    const int blk = blockIdx.x, tid = threadIdx.x;
    const float* src; u16* dst; int idx;
    if (blk < 2048) { src = x; dst = xb; idx = blk * 256 + tid; }
    else {
        const int b2 = blk - 2048, which = b2 >> 9;
        src = (which == 0) ? w0 : (which == 1) ? w1 : (which == 2) ? w2 : w3;
        dst = wb + ((size_t)which << 20);
        idx = (b2 & 511) * 256 + tid;
    }
    const float4* in4 = (const float4*)src;
    const float4 a = in4[idx * 2], b = in4[idx * 2 + 1];
    s16x8 v;
    v[0] = (short)to_f16(a.x); v[1] = (short)to_f16(a.y);
    v[2] = (short)to_f16(a.z); v[3] = (short)to_f16(a.w);
    v[4] = (short)to_f16(b.x); v[5] = (short)to_f16(b.y);
    v[6] = (short)to_f16(b.z); v[7] = (short)to_f16(b.w);
    *(s16x8*)(dst + (size_t)idx * 8) = v;
}

// ---------------------------------------------------------------------------
// Group K-loop, 64x128 (MxN) tile, BK=32, double-buffered, per-group LDS.
// Each wave: 1 A-chunk + 2 B-chunks staged per iter; frags af[4] (M=64),
// bf[2] (wave's 32-wide N slice); 8 MFMA : 6 ds_read.
// SWAP=true computes C^T (A-op=W-frags, B-op=x-frags) for vector epilogues.
// ---------------------------------------------------------------------------
template <bool SWAP>
__device__ __forceinline__ void kloop(
    const u16* __restrict__ Ag, const u16* __restrict__ Wg,
    u16* Abase, u16* Bbase, const int K, const int KH,
    const int ca, const int cb0, const int cb1,
    const int lane, const int wn, f32x4 (&acc)[4][2])
{
    // prologue: group's k-chunk 0 -> buffer 0
    load_lds16(Ag + (size_t)ca  * 16 * K, Abase + ca  * 512);
    load_lds16(Wg + (size_t)cb0 * 16 * K, Bbase + cb0 * 512);
    load_lds16(Wg + (size_t)cb1 * 16 * K, Bbase + cb1 * 512);

    for (int k0 = 0; k0 < KH; k0 += 32) {
        const int buf = (k0 >> 5) & 1;
        __syncthreads();   // drains this buffer's loads (in flight one iter)
        if (k0 + 32 < KH) {
            const int nb_ = buf ^ 1;
            load_lds16(Ag + (size_t)ca  * 16 * K + k0 + 32, Abase + nb_ * 2048 + ca  * 512);
            load_lds16(Wg + (size_t)cb0 * 16 * K + k0 + 32, Bbase + nb_ * 4096 + cb0 * 512);
            load_lds16(Wg + (size_t)cb1 * 16 * K + k0 + 32, Bbase + nb_ * 4096 + cb1 * 512);
        }
        const u16* Acur = Abase + buf * 2048;
        const u16* Bcur = Bbase + buf * 4096;

        s16x8 af[4], bf2[2];
#pragma unroll
        for (int i = 0; i < 4; ++i) {
            const int row = i * 16 + (lane & 15);
            const int u   = (lane >> 4) ^ (row & 3);
            af[i] = *(const s16x8*)(Acur + (size_t)row * 32 + u * 8);
        }
#pragma unroll
        for (int j = 0; j < 2; ++j) {
            const int row = wn + j * 16 + (lane & 15);
            const int u   = (lane >> 4) ^ (row & 3);
            bf2[j] = *(const s16x8*)(Bcur + (size_t)row * 32 + u * 8);
        }
#pragma unroll
        for (int i = 0; i < 4; ++i)
#pragma unroll
            for (int j = 0; j < 2; ++j)
                acc[i][j] = SWAP ? mfma32(bf2[j], af[i], acc[i][j])
                                 : mfma32(af[i], bf2[j], acc[i][j]);
    }
}

// ---------------------------------------------------------------------------
// Split-K MFMA GEMM, 64x128 tile: C = A @ W^T + bias. A:[M,K] f16, W:[N,K].
// 512 threads = 2 groups x 4 waves; group g computes K-half g into fp32
// partials; 48KB LDS -> 3 blocks/CU = 24 waves/CU (R9's 128-tile had 16
// and sat at MfmaUtil 21% latency-exposed; proj's 256-block grid was worse).
// Grids: QKV (24,64)=1536 blocks, proj (8,64)=512 blocks.
// MODE 1 (QKV, N-space = 3 concatenated weights):
//   Q (SWAP): f16 [B,H,S,HD] pre-scaled 0.125; K (SWAP) unscaled; f16x4 stores.
//   V (no swap): f16 [B,H,HD,S], kv-perm p=(kv>>5)*32+quad*8+((kv>>4)&1)*4+(kv&3)
//     baked into each 64-wide s-tile so attn PV reads contiguous b128 A-frags.
// MODE 0 (SWAP): single matrix, fp32 [M,N] out, float4 stores.
// ---------------------------------------------------------------------------
template <int MODE>
__global__ __launch_bounds__(512) void gemm_mfma(
    const u16* __restrict__ A, const u16* __restrict__ Wb,
    const float* __restrict__ b0, const float* __restrict__ b1,
    const float* __restrict__ b2,
    float* __restrict__ outf, u16* __restrict__ outq, u16* __restrict__ outv,
    const int K)
{
    // 48KB: As [grp][buf][64x32] (16KB) | Bs [grp][buf][128x32] (32KB);
    // epilogue fp32 overlay (32KB) reuses it.
    __shared__ u16 smem[24576];
    u16* As = smem;
    u16* Bs = smem + 8192;

    const int tid = threadIdx.x, lane = tid & 63, wid = tid >> 6;
    const int grp = wid >> 2, w4 = wid & 3;
    const int quad = lane >> 4;
    const int bm = blockIdx.y * 64;
    const int nb = blockIdx.x * 128;      // col in (possibly concatenated) N space
    const int which = nb >> 10;           // 0..2 in MODE 1, always 0 in MODE 0
    const int ncol  = nb & 1023;
    const int KH = K >> 1;
    const u16* Wblk = Wb + ((size_t)which << 20) + (size_t)ncol * K;

    // staging: chunk c = 16 rows; lane -> row c*16+(lane>>2), physical 16B
    // unit pu=lane&3 holds global unit lu = pu ^ (row&3)
    const int srow = lane >> 2;
    const int lu   = (lane & 3) ^ (srow & 3);
    const u16* Ag = A    + (size_t)(bm + srow) * K + grp * KH + lu * 8;
    const u16* Wg = Wblk + (size_t)srow       * K + grp * KH + lu * 8;
    const int ca = w4, cb0 = w4 * 2, cb1 = cb0 + 1;
    u16* Abase = As + grp * 4096;
    u16* Bbase = Bs + grp * 8192;

    f32x4 acc[4][2];
#pragma unroll
    for (int i = 0; i < 4; ++i)
#pragma unroll
        for (int j = 0; j < 2; ++j) { f32x4 z = {0.f, 0.f, 0.f, 0.f}; acc[i][j] = z; }

    const int wn = w4 * 32;
    const bool swap = (MODE == 0) || (which < 2);
    if (swap) kloop<true>(Ag, Wg, Abase, Bbase, K, KH, ca, cb0, cb1, lane, wn, acc);
    else      kloop<false>(Ag, Wg, Abase, Bbase, K, KH, ca, cb0, cb1, lane, wn, acc);

    // ---- merge K-half partials via LDS overlay (exact fp32 adds) ----
    // 8 panels of 1024 floats; lane stride 16B -> conflict-free b128.
    __syncthreads();   // all staging reads done; safe to overlay smem
    float* rp = (float*)smem;
    const int slot = (w4 * 64 + lane) * 4;
    if (grp == 1) {
#pragma unroll
        for (int i = 0; i < 4; ++i)
#pragma unroll
            for (int j = 0; j < 2; ++j)
                *(f32x4*)(rp + (i * 2 + j) * 1024 + slot) = acc[i][j];
    }
    __syncthreads();
    if (grp != 0) return;
#pragma unroll
    for (int i = 0; i < 4; ++i)
#pragma unroll
        for (int j = 0; j < 2; ++j)
            acc[i][j] += *(const f32x4*)(rp + (i * 2 + j) * 1024 + slot);

    if (MODE == 0) {
        // C^T: rows = n (tile j, quad*4+r), cols = m (tile i, lane&15)
#pragma unroll
        for (int j = 0; j < 2; ++j) {
            const int n0 = nb + wn + 16 * j + quad * 4;
            const float4 bv = *(const float4*)&b0[n0];
#pragma unroll
            for (int i = 0; i < 4; ++i) {
                const int m = bm + 16 * i + (lane & 15);
                f32x4 w = acc[i][j];
                w[0] += bv.x; w[1] += bv.y; w[2] += bv.z; w[3] += bv.w;
                *(f32x4*)&outf[(size_t)m * 1024 + n0] = w;
            }
        }
    } else if (which < 2) {
        // Q/K (swapped): 4 contiguous hd per lane -> f16x4 stores
        const float* bias = which ? b1 : b0;
        const float scale = which ? 1.0f : 0.125f;   // fold 1/sqrt(HD) into Q
        u16* outb = outq + ((size_t)which << 22);
#pragma unroll
        for (int j = 0; j < 2; ++j) {
            const int nl0 = ncol + wn + 16 * j + quad * 4;
            const float4 bv = *(const float4*)&bias[nl0];
            const int h = nl0 >> 6, hd0 = nl0 & 63;
#pragma unroll
            for (int i = 0; i < 4; ++i) {
                const int m = bm + 16 * i + (lane & 15);
                const int b_ = m >> 11, s = m & 2047;
                f16x4 w;
                w[0] = (_Float16)((acc[i][j][0] + bv.x) * scale);
                w[1] = (_Float16)((acc[i][j][1] + bv.y) * scale);
                w[2] = (_Float16)((acc[i][j][2] + bv.z) * scale);
                w[3] = (_Float16)((acc[i][j][3] + bv.w) * scale);
                *(f16x4*)&outb[(((size_t)(b_ * HH + h)) * SS + s) * HDD + hd0] = w;
            }
        }
    } else {
        // V (unswapped): rows = s (kv), cols = hd. kv = i*16 + quad*4 + r
        // -> p = (i>>1)*32 + quad*8 + (i&1)*4 + r (contiguous in r).
        const int kt = (bm & 2047) >> 6;
        const int b_ = bm >> 11;
#pragma unroll
        for (int j = 0; j < 2; ++j) {
            const int nl = ncol + wn + 16 * j + (lane & 15);
            const float bb = b2[nl];
            const int h = nl >> 6, hd = nl & 63;
            u16* vrow = outv + (((size_t)(b_ * HH + h)) * HDD + hd) * SS + kt * 64;
#pragma unroll
            for (int i = 0; i < 4; ++i) {
                const int p0 = (i >> 1) * 32 + quad * 8 + (i & 1) * 4;
                f16x4 w;
                w[0] = (_Float16)(acc[i][j][0] + bb);
                w[1] = (_Float16)(acc[i][j][1] + bb);
                w[2] = (_Float16)(acc[i][j][2] + bb);
                w[3] = (_Float16)(acc[i][j][3] + bb);
                *(f16x4*)&vrow[p0] = w;
            }
        }
    }
}

// ---------------------------------------------------------------------------
// MFMA flash attention v3 (unchanged from R8/R9): transposed-S, no max-
// subtraction, in-block kv-split. 512 threads = 2 groups x 4 waves; group g
// processes kv half over the same BQ=128 q-rows (2 subtiles/wave, 2:1
// MFMA:ds_read reuse); cross-group merge is a plain sum in an LDS epilogue.
// l via ones-MFMA; P packed with cvt_pkrtz from S^T C-layout registers.
// 43.9 us at ~832 TF-equivalent -- near the m97-structure plateau.
// ---------------------------------------------------------------------------
__global__ __launch_bounds__(512, 4) void attn_mfma(
    const u16* __restrict__ Q, const u16* __restrict__ Kg,
    const u16* __restrict__ Vt, u16* __restrict__ ctx)
{
    // 64KB: [grp][buf] K tiles (32KB) + V tiles (32KB); epilogue overlays it
    __shared__ u16 smem[32768];

    const int tid = threadIdx.x, lane = tid & 63, wid = tid >> 6;
    const int grp = wid >> 2, w4 = wid & 3;
    const int quad = lane >> 4;
    const int bh = blockIdx.y, q0 = blockIdx.x * 128;
    const u16* Qb = Q  + (size_t)bh * SS * HDD;
    const u16* Kb = Kg + (size_t)bh * SS * HDD + (size_t)grp * 1024 * HDD;
    const u16* Vb = Vt + (size_t)bh * HDD * SS + grp * 1024;

    u16* Kbase = smem + grp * 8192;            // + buf*4096
    u16* Vbase = smem + 16384 + grp * 8192;

    // Q B-frags for two q-subtiles: n=q=lane&15, k=quad*8+{0..7} (+32 chunk 1)
    const int qa = q0 + w4 * 32 + (lane & 15);
    const s16x8 bq0a = *(const s16x8*)(Qb + (size_t)qa * HDD + quad * 8);
    const s16x8 bq1a = *(const s16x8*)(Qb + (size_t)qa * HDD + 32 + quad * 8);
    const s16x8 bq0b = *(const s16x8*)(Qb + (size_t)(qa + 16) * HDD + quad * 8);
    const s16x8 bq1b = *(const s16x8*)(Qb + (size_t)(qa + 16) * HDD + 32 + quad * 8);

    f32x4 oa[4], ob[4];   // O^T: C[m=hd(16m + quad*4+r)][n=q=lane&15]
    f32x4 la4 = {0.f, 0.f, 0.f, 0.f}, lb4 = {0.f, 0.f, 0.f, 0.f};
#pragma unroll
    for (int m = 0; m < 4; ++m) {
        f32x4 z = {0.f, 0.f, 0.f, 0.f};
        oa[m] = z; ob[m] = z;
    }
    const s16x8 ones = {15360, 15360, 15360, 15360,
                        15360, 15360, 15360, 15360};  // f16 1.0 x8

    // staging: chunk c (0..7) = 1KB = 8 rows of 128B;
    // physical unit p=c*64+lane -> row p>>3, holds global unit (lane&7)^(row&7)
    const int c0 = w4 * 2, c1 = c0 + 1;
    const int r0 = (c0 * 64 + lane) >> 3, lu0 = ((lane & 7) ^ (r0 & 7));
    const int r1 = (c1 * 64 + lane) >> 3, lu1 = ((lane & 7) ^ (r1 & 7));
    const u16* Kp0 = Kb + (size_t)r0 * HDD + lu0 * 8;
    const u16* Kp1 = Kb + (size_t)r1 * HDD + lu1 * 8;
    const u16* Vp0 = Vb + (size_t)r0 * SS + lu0 * 8;
    const u16* Vp1 = Vb + (size_t)r1 * SS + lu1 * 8;

    // prologue: group's tile 0 -> buffer 0
    load_lds16(Kp0, Kbase + c0 * 512);
    load_lds16(Kp1, Kbase + c1 * 512);
    load_lds16(Vp0, Vbase + c0 * 512);
    load_lds16(Vp1, Vbase + c1 * 512);

    for (int kt = 0; kt < 16; ++kt) {
        const int buf = kt & 1;
        __syncthreads();   // drains this buffer's loads (in flight one iter)

        if (kt + 1 < 16) {   // prefetch group's next tile into other buffer
            const int nb_ = (buf ^ 1) * 4096;
            load_lds16(Kp0 + (size_t)(kt + 1) * 64 * HDD, Kbase + nb_ + c0 * 512);
            load_lds16(Kp1 + (size_t)(kt + 1) * 64 * HDD, Kbase + nb_ + c1 * 512);
            load_lds16(Vp0 + (kt + 1) * 64, Vbase + nb_ + c0 * 512);
            load_lds16(Vp1 + (kt + 1) * 64, Vbase + nb_ + c1 * 512);
        }
        const u16* Kbuf = Kbase + buf * 4096;
        const u16* Vbuf = Vbase + buf * 4096;

        // ---- S^T tiles j (keys 16j..16j+15): shared A=K[key][hd], B=Q regs ----
        f32x4 Sa[4], Sb[4];
#pragma unroll
        for (int j = 0; j < 4; ++j) {
            const int row = j * 16 + (lane & 15);       // key row in tile
            const int sw = lane & 7;                    // row&7 == lane&7
            const s16x8 ak0 = *(const s16x8*)(Kbuf + (size_t)row * 64 + ((quad    ) ^ sw) * 8);
            const s16x8 ak1 = *(const s16x8*)(Kbuf + (size_t)row * 64 + ((quad + 4) ^ sw) * 8);
            f32x4 za = {0.f, 0.f, 0.f, 0.f};
            za = mfma32(ak0, bq0a, za);
            za = mfma32(ak1, bq1a, za);
            Sa[j] = za;
            f32x4 zb = {0.f, 0.f, 0.f, 0.f};
            zb = mfma32(ak0, bq0b, zb);
            zb = mfma32(ak1, bq1b, zb);
            Sb[j] = zb;
        }

        // ---- P = exp(S) (Q pre-scaled), pack via cvt_pkrtz into B-operands ----
        f16x8 pb0a, pb1a, pb0b, pb1b;
        {
            u32x4 u;
            u[0] = __builtin_bit_cast(unsigned int, __builtin_amdgcn_cvt_pkrtz(__expf(Sa[0][0]), __expf(Sa[0][1])));
            u[1] = __builtin_bit_cast(unsigned int, __builtin_amdgcn_cvt_pkrtz(__expf(Sa[0][2]), __expf(Sa[0][3])));
            u[2] = __builtin_bit_cast(unsigned int, __builtin_amdgcn_cvt_pkrtz(__expf(Sa[1][0]), __expf(Sa[1][1])));
            u[3] = __builtin_bit_cast(unsigned int, __builtin_amdgcn_cvt_pkrtz(__expf(Sa[1][2]), __expf(Sa[1][3])));
            pb0a = __builtin_bit_cast(f16x8, u);
            u[0] = __builtin_bit_cast(unsigned int, __builtin_amdgcn_cvt_pkrtz(__expf(Sa[2][0]), __expf(Sa[2][1])));
            u[1] = __builtin_bit_cast(unsigned int, __builtin_amdgcn_cvt_pkrtz(__expf(Sa[2][2]), __expf(Sa[2][3])));
            u[2] = __builtin_bit_cast(unsigned int, __builtin_amdgcn_cvt_pkrtz(__expf(Sa[3][0]), __expf(Sa[3][1])));
            u[3] = __builtin_bit_cast(unsigned int, __builtin_amdgcn_cvt_pkrtz(__expf(Sa[3][2]), __expf(Sa[3][3])));
            pb1a = __builtin_bit_cast(f16x8, u);
            u[0] = __builtin_bit_cast(unsigned int, __builtin_amdgcn_cvt_pkrtz(__expf(Sb[0][0]), __expf(Sb[0][1])));
            u[1] = __builtin_bit_cast(unsigned int, __builtin_amdgcn_cvt_pkrtz(__expf(Sb[0][2]), __expf(Sb[0][3])));
            u[2] = __builtin_bit_cast(unsigned int, __builtin_amdgcn_cvt_pkrtz(__expf(Sb[1][0]), __expf(Sb[1][1])));
            u[3] = __builtin_bit_cast(unsigned int, __builtin_amdgcn_cvt_pkrtz(__expf(Sb[1][2]), __expf(Sb[1][3])));
            pb0b = __builtin_bit_cast(f16x8, u);
            u[0] = __builtin_bit_cast(unsigned int, __builtin_amdgcn_cvt_pkrtz(__expf(Sb[2][0]), __expf(Sb[2][1])));
            u[1] = __builtin_bit_cast(unsigned int, __builtin_amdgcn_cvt_pkrtz(__expf(Sb[2][2]), __expf(Sb[2][3])));
            u[2] = __builtin_bit_cast(unsigned int, __builtin_amdgcn_cvt_pkrtz(__expf(Sb[3][0]), __expf(Sb[3][1])));
            u[3] = __builtin_bit_cast(unsigned int, __builtin_amdgcn_cvt_pkrtz(__expf(Sb[3][2]), __expf(Sb[3][3])));
            pb1b = __builtin_bit_cast(f16x8, u);
        }

        // ---- l via ones-MFMA: C[m][q] = sum_k P[k][q] (all m rows equal) ----
        la4 = mfma32_ff(ones, pb0a, la4);
        la4 = mfma32_ff(ones, pb1a, la4);
        lb4 = mfma32_ff(ones, pb0b, lb4);
        lb4 = mfma32_ff(ones, pb1b, lb4);

        // ---- O^T += Vt·P^T : shared A=Vt frags (kv-perm baked in) ----
#pragma unroll
        for (int m = 0; m < 4; ++m) {
            const int row = m * 16 + (lane & 15);       // hd row in Vt tile
            const int sw = lane & 7;
            const s16x8 v0 = *(const s16x8*)(Vbuf + (size_t)row * 64 + ((quad    ) ^ sw) * 8);
            const s16x8 v1 = *(const s16x8*)(Vbuf + (size_t)row * 64 + ((quad + 4) ^ sw) * 8);
            oa[m] = mfma32_ff(v0, pb0a, oa[m]);
            oa[m] = mfma32_ff(v1, pb1a, oa[m]);
            ob[m] = mfma32_ff(v0, pb0b, ob[m]);
            ob[m] = mfma32_ff(v1, pb1b, ob[m]);
        }
    }

    // ---- cross-group merge via LDS (plain sums; no-max softmax) ----
    // layout: float O[slot=w4*2+sub][q=16][hd=64 pad->68], then l[slot][16]
    __syncthreads();   // all staging reads done; safe to overlay smem
    float* ep = (float*)smem;
    float* lp = ep + 8 * 1088;
    if (grp == 1) {
#pragma unroll
        for (int sub = 0; sub < 2; ++sub) {
            const float* src = (sub == 0) ? (const float*)&oa[0] : (const float*)&ob[0];
            float* base = ep + (w4 * 2 + sub) * 1088 + (lane & 15) * 68 + quad * 4;
#pragma unroll
            for (int m = 0; m < 4; ++m)
                *(f32x4*)(base + m * 16) = *(const f32x4*)(src + m * 4);
        }
        if (quad == 0) {
            lp[(w4 * 2 + 0) * 16 + (lane & 15)] = la4[0];
            lp[(w4 * 2 + 1) * 16 + (lane & 15)] = lb4[0];
        }
    }
    __syncthreads();
    if (grp == 0) {
        const int b_ = bh >> 4, h = bh & 15;
#pragma unroll
        for (int sub = 0; sub < 2; ++sub) {
            const f32x4* own = (sub == 0) ? &oa[0] : &ob[0];
            const float lown = (sub == 0) ? la4[0] : lb4[0];
            const float inv = 1.f / (lown + lp[(w4 * 2 + sub) * 16 + (lane & 15)]);
            const float* base = ep + (w4 * 2 + sub) * 1088 + (lane & 15) * 68 + quad * 4;
            const int s_idx = q0 + w4 * 32 + sub * 16 + (lane & 15);
            u16* orow = ctx + ((size_t)(b_ * SS + s_idx)) * DD + h * HDD;
#pragma unroll
            for (int m = 0; m < 4; ++m) {
                const f32x4 part = *(const f32x4*)(base + m * 16);
                f16x4 w;
#pragma unroll
                for (int r = 0; r < 4; ++r)
                    w[r] = (_Float16)((own[m][r] + part[r]) * inv);
                *(f16x4*)(orow + m * 16 + quad * 4) = w;
            }
        }
    }
}

// ---------------------------------------------------------------------------
extern "C" void kernel_launch(void* const* d_in, const int* in_sizes, int n_in,
                              void* d_out, int out_size, void* d_ws, size_t ws_size,
                              hipStream_t stream)
{
    const float* x  = (const float*)d_in[0];
    const float* wq = (const float*)d_in[1];
    const float* bq = (const float*)d_in[2];
    const float* wk = (const float*)d_in[3];
    const float* bk = (const float*)d_in[4];
    const float* wv = (const float*)d_in[5];
    const float* bv = (const float*)d_in[6];
    const float* wo = (const float*)d_in[7];
    const float* bo = (const float*)d_in[8];

    u16* xb   = (u16*)d_ws;                 // 4M  : x f16
    u16* wb   = xb  + ((size_t)4  << 20);   // 4M  : wq,wk,wv,wo f16
    u16* qk   = wb  + ((size_t)4  << 20);   // 8M  : q,k  [B,H,S,HD] (q pre-scaled)
    u16* vtw  = qk  + ((size_t)8  << 20);   // 4M  : v^T  [B,H,HD,S] (kv-perm tiles)
    u16* ctxb = vtw + ((size_t)4  << 20);   // 4M  : ctx  [B,S,D]

    cast_all<<<4096, 256, 0, stream>>>(x, wq, wk, wv, wo, xb, wb);

    // fused QKV: N-space = 3*1024; V written transposed+permuted
    gemm_mfma<1><<<dim3(24, 64), 512, 0, stream>>>(
        xb, wb, bq, bk, bv, nullptr, qk, vtw, DD);

    attn_mfma<<<dim3(16, 32), 512, 0, stream>>>(
        qk, qk + ((size_t)4 << 20), vtw, ctxb);

    gemm_mfma<0><<<dim3(8, 64), 512, 0, stream>>>(
        ctxb, wb + ((size_t)3 << 20), bo, nullptr, nullptr,
        (float*)d_out, nullptr, nullptr, DD);
}

// Round 11
// 194.935 us; speedup vs baseline: 1.0185x; 1.0185x over previous
//
#include <hip/hip_runtime.h>
#include <math.h>
#include <stdint.h>

// Problem constants (B=2, S=2048, D=1024, H=16, HD=64)
constexpr int BB  = 2;
constexpr int SS  = 2048;
constexpr int DD  = 1024;
constexpr int HH  = 16;
constexpr int HDD = 64;
constexpr int MM  = BB * SS; // 4096

typedef uint16_t u16;
typedef __attribute__((ext_vector_type(4))) float    f32x4;
typedef __attribute__((ext_vector_type(8))) _Float16 f16x8;
typedef __attribute__((ext_vector_type(4))) _Float16 f16x4;
typedef __attribute__((ext_vector_type(8))) short    s16x8;
typedef __attribute__((ext_vector_type(4))) unsigned int u32x4;

__device__ __forceinline__ u16 to_f16(float f) {
    const _Float16 h = (_Float16)f;          // v_cvt_f16_f32, RNE
    return __builtin_bit_cast(u16, h);
}

__device__ __forceinline__ f32x4 mfma32(s16x8 a, s16x8 b, f32x4 c) {
    return __builtin_amdgcn_mfma_f32_16x16x32_f16(
        __builtin_bit_cast(f16x8, a), __builtin_bit_cast(f16x8, b), c, 0, 0, 0);
}
__device__ __forceinline__ f32x4 mfma32_ff(s16x8 a, f16x8 b, f32x4 c) {
    return __builtin_amdgcn_mfma_f32_16x16x32_f16(
        __builtin_bit_cast(f16x8, a), b, c, 0, 0, 0);
}

// async global->LDS, 16B per lane; LDS dest = wave-uniform base + lane*16
__device__ __forceinline__ void load_lds16(const void* g, void* l) {
    __builtin_amdgcn_global_load_lds(
        (const __attribute__((address_space(1))) void*)g,
        (__attribute__((address_space(3))) void*)l, 16, 0, 0);
}

// ---------------------------------------------------------------------------
// fp32 -> fp16 cast, all 5 tensors in one launch.
// blocks 0..2047: x (4M elems); blocks 2048..4095: wq,wk,wv,wo (1M each).
// ---------------------------------------------------------------------------
__global__ __launch_bounds__(256) void cast_all(
    const float* __restrict__ x,
    const float* __restrict__ w0, const float* __restrict__ w1,
    const float* __restrict__ w2, const float* __restrict__ w3,
    u16* __restrict__ xb, u16* __restrict__ wb)
{
    const int blk = blockIdx.x, tid = threadIdx.x;
    const float* src; u16* dst; int idx;
    if (blk < 2048) { src = x; dst = xb; idx = blk * 256 + tid; }
    else {
        const int b2 = blk - 2048, which = b2 >> 9;
        src = (which == 0) ? w0 : (which == 1) ? w1 : (which == 2) ? w2 : w3;
        dst = wb + ((size_t)which << 20);
        idx = (b2 & 511) * 256 + tid;
    }
    const float4* in4 = (const float4*)src;
    const float4 a = in4[idx * 2], b = in4[idx * 2 + 1];
    s16x8 v;
    v[0] = (short)to_f16(a.x); v[1] = (short)to_f16(a.y);
    v[2] = (short)to_f16(a.z); v[3] = (short)to_f16(a.w);
    v[4] = (short)to_f16(b.x); v[5] = (short)to_f16(b.y);
    v[6] = (short)to_f16(b.z); v[7] = (short)to_f16(b.w);
    *(s16x8*)(dst + (size_t)idx * 8) = v;
}

// ---------------------------------------------------------------------------
// Group K-loop (128x128 tile, BK=32 per iter, double-buffered, per-group
// LDS). With the 4-way split each group runs 8 iters over its K-quarter.
// SWAP=true computes C^T (A-op=W-frags, B-op=x-frags) for vector epilogues.
// ---------------------------------------------------------------------------
template <bool SWAP>
__device__ __forceinline__ void kloop(
    const u16* __restrict__ Ag, const u16* __restrict__ Wg,
    u16* Abase, u16* Bbase, const int K, const int KQ,
    const int c0, const int c1,
    const int lane, const int wm, const int wn, f32x4 (&acc)[4][4])
{
    // prologue: group's k-chunk 0 -> buffer 0
    load_lds16(Ag + (size_t)c0 * 16 * K, Abase + c0 * 512);
    load_lds16(Ag + (size_t)c1 * 16 * K, Abase + c1 * 512);
    load_lds16(Wg + (size_t)c0 * 16 * K, Bbase + c0 * 512);
    load_lds16(Wg + (size_t)c1 * 16 * K, Bbase + c1 * 512);

    for (int k0 = 0; k0 < KQ; k0 += 32) {
        const int buf = (k0 >> 5) & 1;
        __syncthreads();   // drains this buffer's loads (in flight one iter)
        if (k0 + 32 < KQ) {
            const int nb_ = (buf ^ 1) * 4096;
            load_lds16(Ag + (size_t)c0 * 16 * K + k0 + 32, Abase + nb_ + c0 * 512);
            load_lds16(Ag + (size_t)c1 * 16 * K + k0 + 32, Abase + nb_ + c1 * 512);
            load_lds16(Wg + (size_t)c0 * 16 * K + k0 + 32, Bbase + nb_ + c0 * 512);
            load_lds16(Wg + (size_t)c1 * 16 * K + k0 + 32, Bbase + nb_ + c1 * 512);
        }
        const u16* Acur = Abase + buf * 4096;
        const u16* Bcur = Bbase + buf * 4096;

        s16x8 af[4], bf4[4];
#pragma unroll
        for (int i = 0; i < 4; ++i) {
            const int row = wm + i * 16 + (lane & 15);
            const int u   = (lane >> 4) ^ (row & 3);
            af[i] = *(const s16x8*)(Acur + (size_t)row * 32 + u * 8);
        }
#pragma unroll
        for (int j = 0; j < 4; ++j) {
            const int row = wn + j * 16 + (lane & 15);
            const int u   = (lane >> 4) ^ (row & 3);
            bf4[j] = *(const s16x8*)(Bcur + (size_t)row * 32 + u * 8);
        }
#pragma unroll
        for (int i = 0; i < 4; ++i)
#pragma unroll
            for (int j = 0; j < 4; ++j)
                acc[i][j] = SWAP ? mfma32(bf4[j], af[i], acc[i][j])
                                 : mfma32(af[i], bf4[j], acc[i][j]);
    }
}

// ---------------------------------------------------------------------------
// 4-way split-K MFMA GEMM, 128x128 tile: C = A @ W^T + bias.
// 1024 threads = 4 groups x 4 waves; group g computes K-quarter g (8 iters)
// into fp32 partials with private dbuf staging (128KB LDS -> 1 block/CU,
// 16 waves = 4/SIMD). Rationale (R8-R10): the K-loop is latency-bound at
// ~2000 cyc/iter regardless of waves/CU; all waves share the block barrier,
// so prefetch slack = whole-block per-iter compute. 16 waves' LDS+MFMA work
// (~1500 cyc) finally covers the ~900-cyc HBM drain, and iters/block drops
// 16->8. Two-stage LDS merge tree (grp1->grp0, grp3->grp2->grp0), exact fp32.
// MODE 1 (QKV, N-space = 3 concatenated weights):
//   Q (SWAP): f16 [B,H,S,HD] pre-scaled 0.125; K (SWAP) unscaled; f16x4 stores.
//   V (no swap): f16 [B,H,HD,S], kv-perm p=(kv>>5)*32+quad*8+((kv>>4)&1)*4+(kv&3)
//     baked into each 64-wide s-tile so attn PV reads contiguous b128 A-frags.
// MODE 0 (SWAP): single matrix, fp32 [M,N] out, float4 stores.
// ---------------------------------------------------------------------------
template <int MODE>
__global__ __launch_bounds__(1024) void gemm_mfma(
    const u16* __restrict__ A, const u16* __restrict__ Wb,
    const float* __restrict__ b0, const float* __restrict__ b1,
    const float* __restrict__ b2,
    float* __restrict__ outf, u16* __restrict__ outq, u16* __restrict__ outv,
    const int K)
{
    // 128KB: As [grp][buf][128x32] (64KB) | Bs same (64KB).
    // Merge overlay reuses it as two 64KB fp32 regions.
    __shared__ u16 smem[65536];
    u16* As = smem;
    u16* Bs = smem + 32768;

    const int tid = threadIdx.x, lane = tid & 63, wid = tid >> 6;
    const int grp = wid >> 2, w4 = wid & 3;
    const int quad = lane >> 4;
    const int bm = blockIdx.y * 128;
    const int nb = blockIdx.x * 128;      // col in (possibly concatenated) N space
    const int which = nb >> 10;           // 0..2 in MODE 1, always 0 in MODE 0
    const int ncol  = nb & 1023;
    const int KQ = K >> 2;
    const u16* Wblk = Wb + ((size_t)which << 20) + (size_t)ncol * K;

    // staging: chunk c = 16 rows; lane -> row c*16+(lane>>2), physical 16B
    // unit pu=lane&3 holds global unit lu = pu ^ (row&3)
    const int srow = lane >> 2;
    const int lu   = (lane & 3) ^ (srow & 3);
    const u16* Ag = A    + (size_t)(bm + srow) * K + grp * KQ + lu * 8;
    const u16* Wg = Wblk + (size_t)srow       * K + grp * KQ + lu * 8;
    const int c0 = w4 * 2, c1 = c0 + 1;
    u16* Abase = As + grp * 8192;   // dbuf: 2 x 4096 u16
    u16* Bbase = Bs + grp * 8192;

    f32x4 acc[4][4];
#pragma unroll
    for (int i = 0; i < 4; ++i)
#pragma unroll
        for (int j = 0; j < 4; ++j) { f32x4 z = {0.f, 0.f, 0.f, 0.f}; acc[i][j] = z; }

    const int wm = (w4 >> 1) * 64, wn = (w4 & 1) * 64;
    const bool swap = (MODE == 0) || (which < 2);
    if (swap) kloop<true>(Ag, Wg, Abase, Bbase, K, KQ, c0, c1, lane, wm, wn, acc);
    else      kloop<false>(Ag, Wg, Abase, Bbase, K, KQ, c0, c1, lane, wm, wn, acc);

    // ---- two-stage merge of 4 K-quarter partials via LDS (exact fp32) ----
    // region r = 16 panels of 1024 floats (64KB); lane stride 16B -> b128,
    // conflict-free.
    float* rp = (float*)smem;
    const int slot = (w4 * 64 + lane) * 4;
    __syncthreads();   // all staging reads done; safe to overlay smem
    if (grp == 1 || grp == 3) {
        float* reg = rp + (grp >> 1) * 16384;
#pragma unroll
        for (int i = 0; i < 4; ++i)
#pragma unroll
            for (int j = 0; j < 4; ++j)
                *(f32x4*)(reg + (i * 4 + j) * 1024 + slot) = acc[i][j];
    }
    __syncthreads();
    if (grp == 0) {
#pragma unroll
        for (int i = 0; i < 4; ++i)
#pragma unroll
            for (int j = 0; j < 4; ++j)
                acc[i][j] += *(const f32x4*)(rp + (i * 4 + j) * 1024 + slot);
    } else if (grp == 2) {
        float* reg = rp + 16384;
#pragma unroll
        for (int i = 0; i < 4; ++i)
#pragma unroll
            for (int j = 0; j < 4; ++j) {
                acc[i][j] += *(const f32x4*)(reg + (i * 4 + j) * 1024 + slot);
                *(f32x4*)(reg + (i * 4 + j) * 1024 + slot) = acc[i][j];
            }
    }
    __syncthreads();
    if (grp != 0) return;
#pragma unroll
    for (int i = 0; i < 4; ++i)
#pragma unroll
        for (int j = 0; j < 4; ++j)
            acc[i][j] += *(const f32x4*)(rp + 16384 + (i * 4 + j) * 1024 + slot);

    if (MODE == 0) {
        // C^T: rows = n (tile j, quad*4+r), cols = m (tile i, lane&15)
#pragma unroll
        for (int j = 0; j < 4; ++j) {
            const int n0 = nb + wn + 16 * j + quad * 4;
            const float4 bv = *(const float4*)&b0[n0];
#pragma unroll
            for (int i = 0; i < 4; ++i) {
                const int m = bm + wm + 16 * i + (lane & 15);
                f32x4 w = acc[i][j];
                w[0] += bv.x; w[1] += bv.y; w[2] += bv.z; w[3] += bv.w;
                *(f32x4*)&outf[(size_t)m * 1024 + n0] = w;
            }
        }
    } else if (which < 2) {
        // Q/K (swapped): 4 contiguous hd per lane -> f16x4 stores
        const float* bias = which ? b1 : b0;
        const float scale = which ? 1.0f : 0.125f;   // fold 1/sqrt(HD) into Q
        u16* outb = outq + ((size_t)which << 22);
        const int h = (ncol + wn) >> 6;
#pragma unroll
        for (int j = 0; j < 4; ++j) {
            const int nl0 = ncol + wn + 16 * j + quad * 4;
            const float4 bv = *(const float4*)&bias[nl0];
            const int hd0 = (nl0 & 63);
#pragma unroll
            for (int i = 0; i < 4; ++i) {
                const int m = bm + wm + 16 * i + (lane & 15);
                const int b_ = m >> 11, s = m & 2047;
                f16x4 w;
                w[0] = (_Float16)((acc[i][j][0] + bv.x) * scale);
                w[1] = (_Float16)((acc[i][j][1] + bv.y) * scale);
                w[2] = (_Float16)((acc[i][j][2] + bv.z) * scale);
                w[3] = (_Float16)((acc[i][j][3] + bv.w) * scale);
                *(f16x4*)&outb[(((size_t)(b_ * HH + h)) * SS + s) * HDD + hd0] = w;
            }
        }
    } else {
        // V (unswapped): rows = s (kv), cols = hd. kv = i*16 + quad*4 + r
        // -> p = (i>>1)*32 + quad*8 + (i&1)*4 + r (contiguous in r).
        const int kt = ((bm + wm) & 2047) >> 6;
        const int b_ = (bm + wm) >> 11;
#pragma unroll
        for (int j = 0; j < 4; ++j) {
            const int nl = ncol + wn + 16 * j + (lane & 15);
            const float bb = b2[nl];
            const int h = nl >> 6, hd = nl & 63;
            u16* vrow = outv + (((size_t)(b_ * HH + h)) * HDD + hd) * SS + kt * 64;
#pragma unroll
            for (int i = 0; i < 4; ++i) {
                const int p0 = (i >> 1) * 32 + quad * 8 + (i & 1) * 4;
                f16x4 w;
                w[0] = (_Float16)(acc[i][j][0] + bb);
                w[1] = (_Float16)(acc[i][j][1] + bb);
                w[2] = (_Float16)(acc[i][j][2] + bb);
                w[3] = (_Float16)(acc[i][j][3] + bb);
                *(f16x4*)&vrow[p0] = w;
            }
        }
    }
}

// ---------------------------------------------------------------------------
// MFMA flash attention v3 (unchanged from R8/R9): transposed-S, no max-
// subtraction, in-block kv-split. 512 threads = 2 groups x 4 waves; group g
// processes kv half over the same BQ=128 q-rows (2 subtiles/wave, 2:1
// MFMA:ds_read reuse); cross-group merge is a plain sum in an LDS epilogue.
// l via ones-MFMA; P packed with cvt_pkrtz from S^T C-layout registers.
// 43.9 us at ~832 TF-equivalent -- near the m97-structure plateau.
// ---------------------------------------------------------------------------
__global__ __launch_bounds__(512, 4) void attn_mfma(
    const u16* __restrict__ Q, const u16* __restrict__ Kg,
    const u16* __restrict__ Vt, u16* __restrict__ ctx)
{
    // 64KB: [grp][buf] K tiles (32KB) + V tiles (32KB); epilogue overlays it
    __shared__ u16 smem[32768];

    const int tid = threadIdx.x, lane = tid & 63, wid = tid >> 6;
    const int grp = wid >> 2, w4 = wid & 3;
    const int quad = lane >> 4;
    const int bh = blockIdx.y, q0 = blockIdx.x * 128;
    const u16* Qb = Q  + (size_t)bh * SS * HDD;
    const u16* Kb = Kg + (size_t)bh * SS * HDD + (size_t)grp * 1024 * HDD;
    const u16* Vb = Vt + (size_t)bh * HDD * SS + grp * 1024;

    u16* Kbase = smem + grp * 8192;            // + buf*4096
    u16* Vbase = smem + 16384 + grp * 8192;

    // Q B-frags for two q-subtiles: n=q=lane&15, k=quad*8+{0..7} (+32 chunk 1)
    const int qa = q0 + w4 * 32 + (lane & 15);
    const s16x8 bq0a = *(const s16x8*)(Qb + (size_t)qa * HDD + quad * 8);
    const s16x8 bq1a = *(const s16x8*)(Qb + (size_t)qa * HDD + 32 + quad * 8);
    const s16x8 bq0b = *(const s16x8*)(Qb + (size_t)(qa + 16) * HDD + quad * 8);
    const s16x8 bq1b = *(const s16x8*)(Qb + (size_t)(qa + 16) * HDD + 32 + quad * 8);

    f32x4 oa[4], ob[4];   // O^T: C[m=hd(16m + quad*4+r)][n=q=lane&15]
    f32x4 la4 = {0.f, 0.f, 0.f, 0.f}, lb4 = {0.f, 0.f, 0.f, 0.f};
#pragma unroll
    for (int m = 0; m < 4; ++m) {
        f32x4 z = {0.f, 0.f, 0.f, 0.f};
        oa[m] = z; ob[m] = z;
    }
    const s16x8 ones = {15360, 15360, 15360, 15360,
                        15360, 15360, 15360, 15360};  // f16 1.0 x8

    // staging: chunk c (0..7) = 1KB = 8 rows of 128B;
    // physical unit p=c*64+lane -> row p>>3, holds global unit (lane&7)^(row&7)
    const int c0 = w4 * 2, c1 = c0 + 1;
    const int r0 = (c0 * 64 + lane) >> 3, lu0 = ((lane & 7) ^ (r0 & 7));
    const int r1 = (c1 * 64 + lane) >> 3, lu1 = ((lane & 7) ^ (r1 & 7));
    const u16* Kp0 = Kb + (size_t)r0 * HDD + lu0 * 8;
    const u16* Kp1 = Kb + (size_t)r1 * HDD + lu1 * 8;
    const u16* Vp0 = Vb + (size_t)r0 * SS + lu0 * 8;
    const u16* Vp1 = Vb + (size_t)r1 * SS + lu1 * 8;

    // prologue: group's tile 0 -> buffer 0
    load_lds16(Kp0, Kbase + c0 * 512);
    load_lds16(Kp1, Kbase + c1 * 512);
    load_lds16(Vp0, Vbase + c0 * 512);
    load_lds16(Vp1, Vbase + c1 * 512);

    for (int kt = 0; kt < 16; ++kt) {
        const int buf = kt & 1;
        __syncthreads();   // drains this buffer's loads (in flight one iter)

        if (kt + 1 < 16) {   // prefetch group's next tile into other buffer
            const int nb_ = (buf ^ 1) * 4096;
            load_lds16(Kp0 + (size_t)(kt + 1) * 64 * HDD, Kbase + nb_ + c0 * 512);
            load_lds16(Kp1 + (size_t)(kt + 1) * 64 * HDD, Kbase + nb_ + c1 * 512);
            load_lds16(Vp0 + (kt + 1) * 64, Vbase + nb_ + c0 * 512);
            load_lds16(Vp1 + (kt + 1) * 64, Vbase + nb_ + c1 * 512);
        }
        const u16* Kbuf = Kbase + buf * 4096;
        const u16* Vbuf = Vbase + buf * 4096;

        // ---- S^T tiles j (keys 16j..16j+15): shared A=K[key][hd], B=Q regs ----
        f32x4 Sa[4], Sb[4];
#pragma unroll
        for (int j = 0; j < 4; ++j) {
            const int row = j * 16 + (lane & 15);       // key row in tile
            const int sw = lane & 7;                    // row&7 == lane&7
            const s16x8 ak0 = *(const s16x8*)(Kbuf + (size_t)row * 64 + ((quad    ) ^ sw) * 8);
            const s16x8 ak1 = *(const s16x8*)(Kbuf + (size_t)row * 64 + ((quad + 4) ^ sw) * 8);
            f32x4 za = {0.f, 0.f, 0.f, 0.f};
            za = mfma32(ak0, bq0a, za);
            za = mfma32(ak1, bq1a, za);
            Sa[j] = za;
            f32x4 zb = {0.f, 0.f, 0.f, 0.f};
            zb = mfma32(ak0, bq0b, zb);
            zb = mfma32(ak1, bq1b, zb);
            Sb[j] = zb;
        }

        // ---- P = exp(S) (Q pre-scaled), pack via cvt_pkrtz into B-operands ----
        f16x8 pb0a, pb1a, pb0b, pb1b;
        {
            u32x4 u;
            u[0] = __builtin_bit_cast(unsigned int, __builtin_amdgcn_cvt_pkrtz(__expf(Sa[0][0]), __expf(Sa[0][1])));
            u[1] = __builtin_bit_cast(unsigned int, __builtin_amdgcn_cvt_pkrtz(__expf(Sa[0][2]), __expf(Sa[0][3])));
            u[2] = __builtin_bit_cast(unsigned int, __builtin_amdgcn_cvt_pkrtz(__expf(Sa[1][0]), __expf(Sa[1][1])));
            u[3] = __builtin_bit_cast(unsigned int, __builtin_amdgcn_cvt_pkrtz(__expf(Sa[1][2]), __expf(Sa[1][3])));
            pb0a = __builtin_bit_cast(f16x8, u);
            u[0] = __builtin_bit_cast(unsigned int, __builtin_amdgcn_cvt_pkrtz(__expf(Sa[2][0]), __expf(Sa[2][1])));
            u[1] = __builtin_bit_cast(unsigned int, __builtin_amdgcn_cvt_pkrtz(__expf(Sa[2][2]), __expf(Sa[2][3])));
            u[2] = __builtin_bit_cast(unsigned int, __builtin_amdgcn_cvt_pkrtz(__expf(Sa[3][0]), __expf(Sa[3][1])));
            u[3] = __builtin_bit_cast(unsigned int, __builtin_amdgcn_cvt_pkrtz(__expf(Sa[3][2]), __expf(Sa[3][3])));
            pb1a = __builtin_bit_cast(f16x8, u);
            u[0] = __builtin_bit_cast(unsigned int, __builtin_amdgcn_cvt_pkrtz(__expf(Sb[0][0]), __expf(Sb[0][1])));
            u[1] = __builtin_bit_cast(unsigned int, __builtin_amdgcn_cvt_pkrtz(__expf(Sb[0][2]), __expf(Sb[0][3])));
            u[2] = __builtin_bit_cast(unsigned int, __builtin_amdgcn_cvt_pkrtz(__expf(Sb[1][0]), __expf(Sb[1][1])));
            u[3] = __builtin_bit_cast(unsigned int, __builtin_amdgcn_cvt_pkrtz(__expf(Sb[1][2]), __expf(Sb[1][3])));
            pb0b = __builtin_bit_cast(f16x8, u);
            u[0] = __builtin_bit_cast(unsigned int, __builtin_amdgcn_cvt_pkrtz(__expf(Sb[2][0]), __expf(Sb[2][1])));
            u[1] = __builtin_bit_cast(unsigned int, __builtin_amdgcn_cvt_pkrtz(__expf(Sb[2][2]), __expf(Sb[2][3])));
            u[2] = __builtin_bit_cast(unsigned int, __builtin_amdgcn_cvt_pkrtz(__expf(Sb[3][0]), __expf(Sb[3][1])));
            u[3] = __builtin_bit_cast(unsigned int, __builtin_amdgcn_cvt_pkrtz(__expf(Sb[3][2]), __expf(Sb[3][3])));
            pb1b = __builtin_bit_cast(f16x8, u);
        }

        // ---- l via ones-MFMA: C[m][q] = sum_k P[k][q] (all m rows equal) ----
        la4 = mfma32_ff(ones, pb0a, la4);
        la4 = mfma32_ff(ones, pb1a, la4);
        lb4 = mfma32_ff(ones, pb0b, lb4);
        lb4 = mfma32_ff(ones, pb1b, lb4);

        // ---- O^T += Vt·P^T : shared A=Vt frags (kv-perm baked in) ----
#pragma unroll
        for (int m = 0; m < 4; ++m) {
            const int row = m * 16 + (lane & 15);       // hd row in Vt tile
            const int sw = lane & 7;
            const s16x8 v0 = *(const s16x8*)(Vbuf + (size_t)row * 64 + ((quad    ) ^ sw) * 8);
            const s16x8 v1 = *(const s16x8*)(Vbuf + (size_t)row * 64 + ((quad + 4) ^ sw) * 8);
            oa[m] = mfma32_ff(v0, pb0a, oa[m]);
            oa[m] = mfma32_ff(v1, pb1a, oa[m]);
            ob[m] = mfma32_ff(v0, pb0b, ob[m]);
            ob[m] = mfma32_ff(v1, pb1b, ob[m]);
        }
    }

    // ---- cross-group merge via LDS (plain sums; no-max softmax) ----
    // layout: float O[slot=w4*2+sub][q=16][hd=64 pad->68], then l[slot][16]
    __syncthreads();   // all staging reads done; safe to overlay smem
    float* ep = (float*)smem;
    float* lp = ep + 8 * 1088;
    if (grp == 1) {
#pragma unroll
        for (int sub = 0; sub < 2; ++sub) {
            const float* src = (sub == 0) ? (const float*)&oa[0] : (const float*)&ob[0];
            float* base = ep + (w4 * 2 + sub) * 1088 + (lane & 15) * 68 + quad * 4;
#pragma unroll
            for (int m = 0; m < 4; ++m)
                *(f32x4*)(base + m * 16) = *(const f32x4*)(src + m * 4);
        }
        if (quad == 0) {
            lp[(w4 * 2 + 0) * 16 + (lane & 15)] = la4[0];
            lp[(w4 * 2 + 1) * 16 + (lane & 15)] = lb4[0];
        }
    }
    __syncthreads();
    if (grp == 0) {
        const int b_ = bh >> 4, h = bh & 15;
#pragma unroll
        for (int sub = 0; sub < 2; ++sub) {
            const f32x4* own = (sub == 0) ? &oa[0] : &ob[0];
            const float lown = (sub == 0) ? la4[0] : lb4[0];
            const float inv = 1.f / (lown + lp[(w4 * 2 + sub) * 16 + (lane & 15)]);
            const float* base = ep + (w4 * 2 + sub) * 1088 + (lane & 15) * 68 + quad * 4;
            const int s_idx = q0 + w4 * 32 + sub * 16 + (lane & 15);
            u16* orow = ctx + ((size_t)(b_ * SS + s_idx)) * DD + h * HDD;
#pragma unroll
            for (int m = 0; m < 4; ++m) {
                const f32x4 part = *(const f32x4*)(base + m * 16);
                f16x4 w;
#pragma unroll
                for (int r = 0; r < 4; ++r)
                    w[r] = (_Float16)((own[m][r] + part[r]) * inv);
                *(f16x4*)(orow + m * 16 + quad * 4) = w;
            }
        }
    }
}

// ---------------------------------------------------------------------------
extern "C" void kernel_launch(void* const* d_in, const int* in_sizes, int n_in,
                              void* d_out, int out_size, void* d_ws, size_t ws_size,
                              hipStream_t stream)
{
    const float* x  = (const float*)d_in[0];
    const float* wq = (const float*)d_in[1];
    const float* bq = (const float*)d_in[2];
    const float* wk = (const float*)d_in[3];
    const float* bk = (const float*)d_in[4];
    const float* wv = (const float*)d_in[5];
    const float* bv = (const float*)d_in[6];
    const float* wo = (const float*)d_in[7];
    const float* bo = (const float*)d_in[8];

    u16* xb   = (u16*)d_ws;                 // 4M  : x f16
    u16* wb   = xb  + ((size_t)4  << 20);   // 4M  : wq,wk,wv,wo f16
    u16* qk   = wb  + ((size_t)4  << 20);   // 8M  : q,k  [B,H,S,HD] (q pre-scaled)
    u16* vtw  = qk  + ((size_t)8  << 20);   // 4M  : v^T  [B,H,HD,S] (kv-perm tiles)
    u16* ctxb = vtw + ((size_t)4  << 20);   // 4M  : ctx  [B,S,D]

    cast_all<<<4096, 256, 0, stream>>>(x, wq, wk, wv, wo, xb, wb);

    // fused QKV: N-space = 3*1024; V written transposed+permuted
    gemm_mfma<1><<<dim3(24, 32), 1024, 0, stream>>>(
        xb, wb, bq, bk, bv, nullptr, qk, vtw, DD);

    attn_mfma<<<dim3(16, 32), 512, 0, stream>>>(
        qk, qk + ((size_t)4 << 20), vtw, ctxb);

    gemm_mfma<0><<<dim3(8, 32), 1024, 0, stream>>>(
        ctxb, wb + ((size_t)3 << 20), bo, nullptr, nullptr,
        (float*)d_out, nullptr, nullptr, DD);
}